// Round 3
// baseline (722.392 us; speedup 1.0000x reference)
//
#include <hip/hip_runtime.h>
#include <math.h>

// Problem constants
#define B_   128
#define E_   512
#define H_   512
#define S_   2048
#define V_   83
#define PAD_ 82

// pe3[e, n]: freq = exp(-ln(10000) * (e&~1)/E); even e -> sin(n*freq), odd -> cos(n*freq)
__device__ __forceinline__ float pe_val(int e, int n) {
    float freq = expf(-9.210340371976184f * (float)(e & ~1) * (1.0f / 512.0f));
    float a = (float)n * freq;
    return (e & 1) ? cosf(a) : sinf(a);
}

// ---- one-time prep -------------------------------------------------------

// W2t[e*1024 + o] = conv_w[o, e, 2]
__global__ void k_prep(const float* __restrict__ cw, float* __restrict__ W2t) {
    int idx = blockIdx.x * 256 + threadIdx.x;        // < 512*1024
    int e = idx >> 10, o = idx & 1023;
    W2t[idx] = cw[o * 1536 + e * 3 + 2];
}

// base[o] = sum_e (embPAD[e]+pe(e,0))*W[o,e,0] + (embPAD[e]+pe(e,1))*W[o,e,1]
__global__ void k_base(const float* __restrict__ cw, const float* __restrict__ emb,
                       float* __restrict__ base) {
    int t = threadIdx.x;                              // block 256, grid 4
    __shared__ float x0[512], x1[512];
    for (int j = t; j < 512; j += 256) {
        float ep = emb[PAD_ * 512 + j];
        x0[j] = ep + pe_val(j, 0);
        x1[j] = ep + pe_val(j, 1);
    }
    __syncthreads();
    int o = blockIdx.x * 256 + t;
    float acc = 0.f;
    for (int e = 0; e < 512; ++e) {
        acc += x0[e] * cw[o * 1536 + e * 3 + 0];
        acc += x1[e] * cw[o * 1536 + e * 3 + 1];
    }
    base[o] = acc;
}

// ---- per-layer kernels ---------------------------------------------------

// xcol[b,e] = (first ? emb[tok[b],e] : h_prev[b,e]) + pe(e,2)
__global__ void k_x(int first, const int* __restrict__ tok, const float* __restrict__ emb,
                    const float* __restrict__ h, float* __restrict__ xcol) {
    int idx = blockIdx.x * 256 + threadIdx.x;        // < 65536
    int b = idx >> 9, e = idx & 511;
    float v = first ? emb[tok[b] * 512 + e] : h[idx];
    xcol[idx] = v + pe_val(e, 2);
}

// y[b,o] = base[o] + conv_b[o] + sum_e xcol[b,e]*W2t[e,o]    (4 batches per block)
__global__ void k_y(const float* __restrict__ xcol, const float* __restrict__ W2t,
                    const float* __restrict__ base, const float* __restrict__ cb,
                    float* __restrict__ y) {
    int oc = blockIdx.x, bq = blockIdx.y, t = threadIdx.x;  // grid (4,32), block 256
    __shared__ float xs[4][512];
    for (int j = t; j < 2048; j += 256) xs[j >> 9][j & 511] = xcol[bq * 2048 + j];
    __syncthreads();
    int o = oc * 256 + t;
    float init = base[o] + cb[o];
    float a0 = init, a1 = init, a2 = init, a3 = init;
    for (int e = 0; e < 512; ++e) {
        float w = W2t[e * 1024 + o];
        a0 += xs[0][e] * w; a1 += xs[1][e] * w;
        a2 += xs[2][e] * w; a3 += xs[3][e] * w;
    }
    int b0 = bq * 4;
    y[(size_t)(b0 + 0) * 1024 + o] = a0;
    y[(size_t)(b0 + 1) * 1024 + o] = a1;
    y[(size_t)(b0 + 2) * 1024 + o] = a2;
    y[(size_t)(b0 + 3) * 1024 + o] = a3;
}

// glu = y[:,:512]*sigmoid(y[:,512:]);  d = glu + xcol
__global__ void k_glud(const float* __restrict__ y, const float* __restrict__ xcol,
                       float* __restrict__ glu, float* __restrict__ dv) {
    int idx = blockIdx.x * 256 + threadIdx.x;        // < 65536
    int b = idx >> 9, hh = idx & 511;
    float ya = y[(size_t)b * 1024 + hh];
    float yb = y[(size_t)b * 1024 + 512 + hh];
    float g = ya / (1.0f + expf(-yb));
    glu[idx] = g;
    dv[idx] = g + xcol[idx];
}

// scores[b,s] = sum_h d[b,h]*enc_out[b,h,s]; grid (8 s-chunks, 128 b), block 256 (4 waves split h)
__global__ void k_scores(const float* __restrict__ dv, const float* __restrict__ enc,
                         float* __restrict__ attn) {
    int sc = blockIdx.x, b = blockIdx.y, t = threadIdx.x;
    int wave = t >> 6, lane = t & 63;
    __shared__ float dl[512];
    __shared__ float red[1024];
    for (int j = t; j < 512; j += 256) dl[j] = dv[b * 512 + j];
    __syncthreads();
    const float* ep = enc + (size_t)b * 512 * 2048 + sc * 256 + lane * 4;
    float a0 = 0, a1 = 0, a2 = 0, a3 = 0;
    int h0 = wave * 128;
    for (int hh = 0; hh < 128; ++hh) {
        float4 v = *(const float4*)(ep + (size_t)(h0 + hh) * 2048);
        float dh = dl[h0 + hh];
        a0 += dh * v.x; a1 += dh * v.y;
        a2 += dh * v.z; a3 += dh * v.w;
    }
    int sl = wave * 256 + lane * 4;
    red[sl + 0] = a0; red[sl + 1] = a1; red[sl + 2] = a2; red[sl + 3] = a3;
    __syncthreads();
    float s = red[t] + red[256 + t] + red[512 + t] + red[768 + t];
    attn[b * 2048 + sc * 256 + t] = s;
}

// in-place softmax over S=2048 per batch
__global__ void k_softmax(float* __restrict__ attn) {
    int b = blockIdx.x, t = threadIdx.x;              // block 256
    float v[8];
    float m = -1e30f;
    for (int i = 0; i < 8; ++i) { v[i] = attn[b * 2048 + i * 256 + t]; m = fmaxf(m, v[i]); }
    __shared__ float r[256];
    r[t] = m; __syncthreads();
    for (int s = 128; s > 0; s >>= 1) { if (t < s) r[t] = fmaxf(r[t], r[t + s]); __syncthreads(); }
    float M = r[0]; __syncthreads();
    float sum = 0.f;
    for (int i = 0; i < 8; ++i) { v[i] = expf(v[i] - M); sum += v[i]; }
    r[t] = sum; __syncthreads();
    for (int s = 128; s > 0; s >>= 1) { if (t < s) r[t] += r[t + s]; __syncthreads(); }
    float inv = 1.0f / r[0];
    for (int i = 0; i < 8; ++i) attn[b * 2048 + i * 256 + t] = v[i] * inv;
}

// c[b,h] = sum_s attn[b,s]*enc_total[b,h,s];  h_out = glu + c.  One wave per (b,h).
__global__ void k_c(const float* __restrict__ attn, const float* __restrict__ enc,
                    const float* __restrict__ glu, float* __restrict__ hbuf) {
    int t = threadIdx.x;                              // block 256 = 4 waves, grid 16384
    int widx = blockIdx.x * 4 + (t >> 6);
    int lane = t & 63;
    int b = widx >> 9, hh = widx & 511;
    const float* vp = enc + (size_t)(b * 512 + hh) * 2048;
    const float* ap = attn + b * 2048;
    float acc = 0.f;
    #pragma unroll
    for (int it = 0; it < 8; ++it) {
        int s = it * 256 + lane * 4;
        float4 w = *(const float4*)(vp + s);
        float4 p = *(const float4*)(ap + s);
        acc += p.x * w.x + p.y * w.y + p.z * w.z + p.w * w.w;
    }
    #pragma unroll
    for (int off = 32; off > 0; off >>= 1) acc += __shfl_down(acc, off, 64);
    if (lane == 0) hbuf[b * 512 + hh] = glu[b * 512 + hh] + acc;
}

// ---- epilogue ------------------------------------------------------------

// logits[b,v] = h3[b,:]·lin2_w[v,:] + lin2_b[v]; out1 = log_softmax over V=83 (f32 out)
__global__ void k_logits(const float* __restrict__ h, const float* __restrict__ l2w,
                         const float* __restrict__ l2b, float* __restrict__ out) {
    int b = blockIdx.x, t = threadIdx.x;              // block 128
    __shared__ float hl[512];
    for (int j = t; j < 512; j += 128) hl[j] = h[b * 512 + j];
    __syncthreads();
    float acc = 0.f;
    if (t < V_) {
        acc = l2b[t];
        for (int e = 0; e < 512; ++e) acc += hl[e] * l2w[t * 512 + e];
    }
    __shared__ float r[128];
    r[t] = (t < V_) ? acc : -1e30f; __syncthreads();
    for (int s = 64; s > 0; s >>= 1) { if (t < s) r[t] = fmaxf(r[t], r[t + s]); __syncthreads(); }
    float M = r[0]; __syncthreads();
    r[t] = (t < V_) ? expf(acc - M) : 0.f; __syncthreads();
    for (int s = 64; s > 0; s >>= 1) { if (t < s) r[t] += r[t + s]; __syncthreads(); }
    float L = M + logf(r[0]);
    if (t < V_) out[65536 + b * V_ + t] = acc - L;
}

// out0 = softmax(h3, axis=H)  (f32 out)
__global__ void k_out0(const float* __restrict__ h, float* __restrict__ out) {
    int b = blockIdx.x, t = threadIdx.x;              // block 256
    float v0 = h[b * 512 + t], v1 = h[b * 512 + 256 + t];
    __shared__ float r[256];
    r[t] = fmaxf(v0, v1); __syncthreads();
    for (int s = 128; s > 0; s >>= 1) { if (t < s) r[t] = fmaxf(r[t], r[t + s]); __syncthreads(); }
    float M = r[0]; __syncthreads();
    float e0 = expf(v0 - M), e1 = expf(v1 - M);
    r[t] = e0 + e1; __syncthreads();
    for (int s = 128; s > 0; s >>= 1) { if (t < s) r[t] += r[t + s]; __syncthreads(); }
    float inv = 1.0f / r[0];
    out[b * 512 + t] = e0 * inv;
    out[b * 512 + 256 + t] = e1 * inv;
}

// ---- launch --------------------------------------------------------------

extern "C" void kernel_launch(void* const* d_in, const int* in_sizes, int n_in,
                              void* d_out, int out_size, void* d_ws, size_t ws_size,
                              hipStream_t stream) {
    const float* enc_out = (const float*)d_in[0];   // [B,H,S] f32
    const float* enc_tot = (const float*)d_in[1];   // [B,H,S] f32
    const int*   tok     = (const int*)d_in[2];     // [B] int32
    // d_in[3] = count (==0 path, unused)
    const float* emb     = (const float*)d_in[4];   // [V,E] f32
    const float* conv_w  = (const float*)d_in[5];   // [1024,512,3] f32
    const float* conv_b  = (const float*)d_in[6];   // [1024] f32
    const float* l2w     = (const float*)d_in[7];   // [83,512] f32
    const float* l2b     = (const float*)d_in[8];   // [83] f32
    float* out = (float*)d_out;                     // 65536 (softmax h3) + 10624 (ls3) f32
    float* ws = (float*)d_ws;

    // ws layout (floats)
    float* W2t  = ws;                 // 524288  (conv_w[:, :, 2] transposed)
    float* base = W2t + 524288;       // 1024
    float* xcol = base + 1024;        // 65536
    float* yb   = xcol + 65536;       // 131072
    float* glu  = yb + 131072;        // 65536
    float* dv   = glu + 65536;        // 65536
    float* attn = dv + 65536;         // 262144
    float* hbuf = attn + 262144;      // 65536
    // total ~4.72 MB

    k_prep<<<2048, 256, 0, stream>>>(conv_w, W2t);
    k_base<<<4, 256, 0, stream>>>(conv_w, emb, base);

    for (int L = 0; L < 3; ++L) {
        k_x<<<256, 256, 0, stream>>>(L == 0 ? 1 : 0, tok, emb, hbuf, xcol);
        k_y<<<dim3(4, 32), 256, 0, stream>>>(xcol, W2t, base, conv_b, yb);
        k_glud<<<256, 256, 0, stream>>>(yb, xcol, glu, dv);
        k_scores<<<dim3(8, 128), 256, 0, stream>>>(dv, enc_out, attn);
        k_softmax<<<128, 256, 0, stream>>>(attn);
        k_c<<<16384, 256, 0, stream>>>(attn, enc_tot, glu, hbuf);
    }

    k_logits<<<128, 128, 0, stream>>>(hbuf, l2w, l2b, out);
    k_out0<<<128, 256, 0, stream>>>(hbuf, out);
}

// Round 4
// 706.245 us; speedup vs baseline: 1.0229x; 1.0229x over previous
//
#include <hip/hip_runtime.h>
#include <math.h>

// Problem constants
#define B_   128
#define E_   512
#define H_   512
#define S_   2048
#define V_   83
#define PAD_ 82

// pe3[e, n]: freq = exp(-ln(10000) * (e&~1)/E); even e -> sin(n*freq), odd -> cos(n*freq)
__device__ __forceinline__ float pe_val(int e, int n) {
    float freq = expf(-9.210340371976184f * (float)(e & ~1) * (1.0f / 512.0f));
    float a = (float)n * freq;
    return (e & 1) ? cosf(a) : sinf(a);
}

// ---- one-time prep -------------------------------------------------------

// W2t[e*1024 + o] = conv_w[o, e, 2]
__global__ void k_prep(const float* __restrict__ cw, float* __restrict__ W2t) {
    int idx = blockIdx.x * 256 + threadIdx.x;        // < 512*1024
    int e = idx >> 10, o = idx & 1023;
    W2t[idx] = cw[o * 1536 + e * 3 + 2];
}

// pe2[e] = pe(e,2); x01i[e*3+{0,1,2}] = {embPAD[e]+pe(e,0), embPAD[e]+pe(e,1), 0}
__global__ void k_misc(const float* __restrict__ emb, float* __restrict__ pe2,
                       float* __restrict__ x01i) {
    int e = threadIdx.x;                              // 1 block, 512 threads
    float freq = expf(-9.210340371976184f * (float)(e & ~1) * (1.0f / 512.0f));
    float p0 = (e & 1) ? 1.0f : 0.0f;                 // cos(0)/sin(0)
    float p1 = (e & 1) ? cosf(freq) : sinf(freq);
    float p2 = (e & 1) ? cosf(2.0f * freq) : sinf(2.0f * freq);
    pe2[e] = p2;
    float ep = emb[PAD_ * 512 + e];
    x01i[e * 3 + 0] = ep + p0;
    x01i[e * 3 + 1] = ep + p1;
    x01i[e * 3 + 2] = 0.0f;
}

// base[o] = dot(conv_w[o, 0:1536], x01i)  — contiguous row reads, wave per o
__global__ void k_base3(const float* __restrict__ cw, const float* __restrict__ x01i,
                        float* __restrict__ base) {
    int t = threadIdx.x, w = t >> 6, lane = t & 63;   // grid 256, block 256
    __shared__ float xs[1536];
    for (int j = t; j < 1536; j += 256) xs[j] = x01i[j];
    __syncthreads();
    int o = blockIdx.x * 4 + w;
    const float* rp = cw + (size_t)o * 1536 + lane * 4;
    float acc = 0.f;
    #pragma unroll
    for (int j = 0; j < 6; ++j) {
        float4 v = *(const float4*)(rp + j * 256);
        const float* xp = &xs[lane * 4 + j * 256];
        acc += v.x * xp[0] + v.y * xp[1] + v.z * xp[2] + v.w * xp[3];
    }
    #pragma unroll
    for (int off = 32; off > 0; off >>= 1) acc += __shfl_down(acc, off, 64);
    if (lane == 0) base[o] = acc;
}

// ---- per-layer kernels ---------------------------------------------------

// xcol[b,e] = (first ? emb[tok[b],e] : h_prev[b,e]) + pe2[e]
__global__ void k_x(int first, const int* __restrict__ tok, const float* __restrict__ emb,
                    const float* __restrict__ h, const float* __restrict__ pe2,
                    float* __restrict__ xcol) {
    int idx = blockIdx.x * 256 + threadIdx.x;        // < 65536
    int b = idx >> 9, e = idx & 511;
    float v = first ? emb[tok[b] * 512 + e] : h[idx];
    xcol[idx] = v + pe2[e];
}

// y[b,o] = base[o] + conv_b[o] + sum_e xcol[b,e]*W2t[e,o]    (4 batches per block)
__global__ void k_y(const float* __restrict__ xcol, const float* __restrict__ W2t,
                    const float* __restrict__ base, const float* __restrict__ cb,
                    float* __restrict__ y) {
    int oc = blockIdx.x, bq = blockIdx.y, t = threadIdx.x;  // grid (4,32), block 256
    __shared__ float xs[4][512];
    for (int j = t; j < 2048; j += 256) xs[j >> 9][j & 511] = xcol[bq * 2048 + j];
    __syncthreads();
    int o = oc * 256 + t;
    float init = base[o] + cb[o];
    float a0 = init, a1 = init, a2 = init, a3 = init;
    for (int e = 0; e < 512; ++e) {
        float w = W2t[e * 1024 + o];
        a0 += xs[0][e] * w; a1 += xs[1][e] * w;
        a2 += xs[2][e] * w; a3 += xs[3][e] * w;
    }
    int b0 = bq * 4;
    y[(size_t)(b0 + 0) * 1024 + o] = a0;
    y[(size_t)(b0 + 1) * 1024 + o] = a1;
    y[(size_t)(b0 + 2) * 1024 + o] = a2;
    y[(size_t)(b0 + 3) * 1024 + o] = a3;
}

// partial scores: grid (8 hc, 128 b), block 256 = 4 waves.
// wave w streams 16 full contiguous rows h = hc*64 + w*16 + r; lane owns s-slots lane*4 + j*256.
// d[b,h] = glu + xcol computed on the fly from y.
__global__ void k_scores2(const float* __restrict__ y, const float* __restrict__ xcol,
                          const float* __restrict__ enc, float* __restrict__ part) {
    int hc = blockIdx.x, b = blockIdx.y, t = threadIdx.x;
    int w = t >> 6, lane = t & 63;
    __shared__ float dl[64];
    __shared__ float red[4 * 2048];
    if (t < 64) {
        int hg = hc * 64 + t;
        float ya = y[b * 1024 + hg];
        float yb_ = y[b * 1024 + 512 + hg];
        float g = ya / (1.0f + expf(-yb_));
        dl[t] = g + xcol[b * 512 + hg];
    }
    __syncthreads();
    float4 a[8];
    #pragma unroll
    for (int j = 0; j < 8; ++j) a[j] = make_float4(0.f, 0.f, 0.f, 0.f);
    const float* bp = enc + ((size_t)b * 512 + hc * 64 + w * 16) * 2048 + lane * 4;
    for (int r = 0; r < 16; ++r) {
        float dh = dl[w * 16 + r];
        const float* rp = bp + (size_t)r * 2048;
        #pragma unroll
        for (int j = 0; j < 8; ++j) {
            float4 v = *(const float4*)(rp + j * 256);
            a[j].x += dh * v.x; a[j].y += dh * v.y;
            a[j].z += dh * v.z; a[j].w += dh * v.w;
        }
    }
    #pragma unroll
    for (int j = 0; j < 8; ++j)
        *(float4*)&red[w * 2048 + j * 256 + lane * 4] = a[j];
    __syncthreads();
    #pragma unroll
    for (int k = 0; k < 2; ++k) {
        int s = t * 4 + k * 1024;
        float4 s0 = *(const float4*)&red[0 * 2048 + s];
        float4 s1 = *(const float4*)&red[1 * 2048 + s];
        float4 s2 = *(const float4*)&red[2 * 2048 + s];
        float4 s3 = *(const float4*)&red[3 * 2048 + s];
        float4 o4 = make_float4(s0.x + s1.x + s2.x + s3.x,
                                s0.y + s1.y + s2.y + s3.y,
                                s0.z + s1.z + s2.z + s3.z,
                                s0.w + s1.w + s2.w + s3.w);
        *(float4*)&part[(size_t)hc * 262144 + b * 2048 + s] = o4;
    }
}

// sum 8 partials + softmax over S=2048 per batch
__global__ void k_softmax2(const float* __restrict__ part, float* __restrict__ attn) {
    int b = blockIdx.x, t = threadIdx.x;              // block 256
    float v[8];
    float m = -1e30f;
    for (int i = 0; i < 8; ++i) {
        int s = i * 256 + t;
        float acc = 0.f;
        #pragma unroll
        for (int hc = 0; hc < 8; ++hc) acc += part[(size_t)hc * 262144 + b * 2048 + s];
        v[i] = acc; m = fmaxf(m, acc);
    }
    __shared__ float r[256];
    r[t] = m; __syncthreads();
    for (int s = 128; s > 0; s >>= 1) { if (t < s) r[t] = fmaxf(r[t], r[t + s]); __syncthreads(); }
    float M = r[0]; __syncthreads();
    float sum = 0.f;
    for (int i = 0; i < 8; ++i) { v[i] = expf(v[i] - M); sum += v[i]; }
    r[t] = sum; __syncthreads();
    for (int s = 128; s > 0; s >>= 1) { if (t < s) r[t] += r[t + s]; __syncthreads(); }
    float inv = 1.0f / r[0];
    for (int i = 0; i < 8; ++i) attn[b * 2048 + i * 256 + t] = v[i] * inv;
}

// c[b,h] = sum_s attn[b,s]*enc_total[b,h,s];  h_out = glu(y) + c.  One wave per (b,h).
__global__ void k_c2(const float* __restrict__ attn, const float* __restrict__ enc,
                     const float* __restrict__ y, float* __restrict__ hbuf) {
    int t = threadIdx.x;                              // block 256 = 4 waves, grid 16384
    int widx = blockIdx.x * 4 + (t >> 6);
    int lane = t & 63;
    int b = widx >> 9, hh = widx & 511;
    const float* vp = enc + (size_t)(b * 512 + hh) * 2048;
    const float* ap = attn + b * 2048;
    float acc = 0.f;
    #pragma unroll
    for (int it = 0; it < 8; ++it) {
        int s = it * 256 + lane * 4;
        float4 w = *(const float4*)(vp + s);
        float4 p = *(const float4*)(ap + s);
        acc += p.x * w.x + p.y * w.y + p.z * w.z + p.w * w.w;
    }
    #pragma unroll
    for (int off = 32; off > 0; off >>= 1) acc += __shfl_down(acc, off, 64);
    if (lane == 0) {
        float ya = y[b * 1024 + hh];
        float yb_ = y[b * 1024 + 512 + hh];
        float g = ya / (1.0f + expf(-yb_));
        hbuf[b * 512 + hh] = g + acc;
    }
}

// ---- epilogue ------------------------------------------------------------

// logits[b,v] = h3[b,:]·lin2_w[v,:] + lin2_b[v]; out1 = log_softmax over V=83 (f32 out)
__global__ void k_logits(const float* __restrict__ h, const float* __restrict__ l2w,
                         const float* __restrict__ l2b, float* __restrict__ out) {
    int b = blockIdx.x, t = threadIdx.x;              // block 128
    __shared__ float hl[512];
    for (int j = t; j < 512; j += 128) hl[j] = h[b * 512 + j];
    __syncthreads();
    float acc = 0.f;
    if (t < V_) {
        acc = l2b[t];
        for (int e = 0; e < 512; ++e) acc += hl[e] * l2w[t * 512 + e];
    }
    __shared__ float r[128];
    r[t] = (t < V_) ? acc : -1e30f; __syncthreads();
    for (int s = 64; s > 0; s >>= 1) { if (t < s) r[t] = fmaxf(r[t], r[t + s]); __syncthreads(); }
    float M = r[0]; __syncthreads();
    r[t] = (t < V_) ? expf(acc - M) : 0.f; __syncthreads();
    for (int s = 64; s > 0; s >>= 1) { if (t < s) r[t] += r[t + s]; __syncthreads(); }
    float L = M + logf(r[0]);
    if (t < V_) out[65536 + b * V_ + t] = acc - L;
}

// out0 = softmax(h3, axis=H)  (f32 out)
__global__ void k_out0(const float* __restrict__ h, float* __restrict__ out) {
    int b = blockIdx.x, t = threadIdx.x;              // block 256
    float v0 = h[b * 512 + t], v1 = h[b * 512 + 256 + t];
    __shared__ float r[256];
    r[t] = fmaxf(v0, v1); __syncthreads();
    for (int s = 128; s > 0; s >>= 1) { if (t < s) r[t] = fmaxf(r[t], r[t + s]); __syncthreads(); }
    float M = r[0]; __syncthreads();
    float e0 = expf(v0 - M), e1 = expf(v1 - M);
    r[t] = e0 + e1; __syncthreads();
    for (int s = 128; s > 0; s >>= 1) { if (t < s) r[t] += r[t + s]; __syncthreads(); }
    float inv = 1.0f / r[0];
    out[b * 512 + t] = e0 * inv;
    out[b * 512 + 256 + t] = e1 * inv;
}

// ---- launch --------------------------------------------------------------

extern "C" void kernel_launch(void* const* d_in, const int* in_sizes, int n_in,
                              void* d_out, int out_size, void* d_ws, size_t ws_size,
                              hipStream_t stream) {
    const float* enc_out = (const float*)d_in[0];   // [B,H,S] f32
    const float* enc_tot = (const float*)d_in[1];   // [B,H,S] f32
    const int*   tok     = (const int*)d_in[2];     // [B] int32
    // d_in[3] = count (==0 path)
    const float* emb     = (const float*)d_in[4];   // [V,E] f32
    const float* conv_w  = (const float*)d_in[5];   // [1024,512,3] f32
    const float* conv_b  = (const float*)d_in[6];   // [1024] f32
    const float* l2w     = (const float*)d_in[7];   // [83,512] f32
    const float* l2b     = (const float*)d_in[8];   // [83] f32
    float* out = (float*)d_out;                     // 65536 + 10624 f32
    float* ws = (float*)d_ws;

    // ws layout (floats)
    float* W2t  = ws;                 // 524288
    float* base = W2t + 524288;       // 1024
    float* pe2  = base + 1024;        // 512
    float* x01i = pe2 + 512;          // 1536
    float* xcol = x01i + 1536;        // 65536
    float* yb   = xcol + 65536;       // 131072
    float* attn = yb + 131072;        // 262144
    float* part = attn + 262144;      // 8*262144 = 2097152
    float* hbuf = part + 2097152;     // 65536
    // total ~12.6 MB

    k_prep<<<2048, 256, 0, stream>>>(conv_w, W2t);
    k_misc<<<1, 512, 0, stream>>>(emb, pe2, x01i);
    k_base3<<<256, 256, 0, stream>>>(conv_w, x01i, base);

    for (int L = 0; L < 3; ++L) {
        k_x<<<256, 256, 0, stream>>>(L == 0 ? 1 : 0, tok, emb, hbuf, pe2, xcol);
        k_y<<<dim3(4, 32), 256, 0, stream>>>(xcol, W2t, base, conv_b, yb);
        k_scores2<<<dim3(8, 128), 256, 0, stream>>>(yb, xcol, enc_out, part);
        k_softmax2<<<128, 256, 0, stream>>>(part, attn);
        k_c2<<<16384, 256, 0, stream>>>(attn, enc_tot, yb, hbuf);
    }

    k_logits<<<128, 128, 0, stream>>>(hbuf, l2w, l2b, out);
    k_out0<<<128, 256, 0, stream>>>(hbuf, out);
}

// Round 5
// 630.191 us; speedup vs baseline: 1.1463x; 1.1207x over previous
//
#include <hip/hip_runtime.h>
#include <math.h>

// Problem constants
#define B_   128
#define E_   512
#define H_   512
#define S_   2048
#define V_   83
#define PAD_ 82

typedef float v4f __attribute__((ext_vector_type(4)));

__device__ __forceinline__ v4f ldnt4(const float* p) {
    return __builtin_nontemporal_load((const v4f*)p);
}

// ---- one-time prep -------------------------------------------------------

// pe2[e] = pe(e,2); x01i[e*3+{0,1,2}] = {embPAD[e]+pe(e,0), embPAD[e]+pe(e,1), 0}
__global__ void k_misc(const float* __restrict__ emb, float* __restrict__ pe2,
                       float* __restrict__ x01i) {
    int e = threadIdx.x;                              // 1 block, 512 threads
    float freq = expf(-9.210340371976184f * (float)(e & ~1) * (1.0f / 512.0f));
    float p0 = (e & 1) ? 1.0f : 0.0f;                 // cos(0)/sin(0)
    float p1 = (e & 1) ? cosf(freq) : sinf(freq);
    float p2 = (e & 1) ? cosf(2.0f * freq) : sinf(2.0f * freq);
    pe2[e] = p2;
    float ep = emb[PAD_ * 512 + e];
    x01i[e * 3 + 0] = ep + p0;
    x01i[e * 3 + 1] = ep + p1;
    x01i[e * 3 + 2] = 0.0f;
}

// base[o] = dot(conv_w[o, 0:1536], x01i)  — contiguous row reads, wave per o
__global__ void k_base3(const float* __restrict__ cw, const float* __restrict__ x01i,
                        float* __restrict__ base) {
    int t = threadIdx.x, w = t >> 6, lane = t & 63;   // grid 256, block 256
    __shared__ float xs[1536];
    for (int j = t; j < 1536; j += 256) xs[j] = x01i[j];
    __syncthreads();
    int o = blockIdx.x * 4 + w;
    const float* rp = cw + (size_t)o * 1536 + lane * 4;
    float acc = 0.f;
    #pragma unroll
    for (int j = 0; j < 6; ++j) {
        float4 v = *(const float4*)(rp + j * 256);
        const float* xp = &xs[lane * 4 + j * 256];
        acc += v.x * xp[0] + v.y * xp[1] + v.z * xp[2] + v.w * xp[3];
    }
    #pragma unroll
    for (int off = 32; off > 0; off >>= 1) acc += __shfl_down(acc, off, 64);
    if (lane == 0) base[o] = acc;
}

// LDS-tiled transpose: W2t[e*1024 + o] = conv_w[o*1536 + e*3 + 2]
// grid (16, 4): 64-o x 128-e tiles; coalesced-ish reads, coalesced writes.
__global__ void k_prep(const float* __restrict__ cw, float* __restrict__ W2t) {
    __shared__ float tile[64][129];                   // +1 pad: conflict-free transpose
    int ob = blockIdx.x * 64, eb = blockIdx.y * 128;
    int t = threadIdx.x;                              // block 256
    for (int idx = t; idx < 8192; idx += 256) {
        int r = idx >> 7, e = idx & 127;
        tile[r][e] = cw[(size_t)(ob + r) * 1536 + (eb + e) * 3 + 2];
    }
    __syncthreads();
    for (int idx = t; idx < 8192; idx += 256) {
        int e = idx >> 6, o = idx & 63;
        W2t[(size_t)(eb + e) * 1024 + ob + o] = tile[o][e];
    }
}

// ---- per-layer kernels ---------------------------------------------------

// fused k_x + k_y: builds xs[4][512] = src + pe2 in LDS (oc==0 also writes xcol),
// then y[b,o] = base[o]+cb[o]+sum_e xs[b][e]*W2t[e,o]
__global__ void k_yx(int first, const int* __restrict__ tok, const float* __restrict__ emb,
                     const float* __restrict__ h, const float* __restrict__ pe2,
                     const float* __restrict__ W2t, const float* __restrict__ base,
                     const float* __restrict__ cb, float* __restrict__ xcol,
                     float* __restrict__ y) {
    int oc = blockIdx.x, bq = blockIdx.y, t = threadIdx.x;  // grid (4,32), block 256
    __shared__ float xs[4][512];
    for (int j = t; j < 2048; j += 256) {
        int bb = j >> 9, e = j & 511;
        int b = bq * 4 + bb;
        float v = first ? emb[tok[b] * 512 + e] : h[b * 512 + e];
        xs[bb][e] = v + pe2[e];
    }
    __syncthreads();
    if (oc == 0)
        for (int j = t; j < 2048; j += 256) xcol[bq * 2048 + j] = xs[j >> 9][j & 511];
    int o = oc * 256 + t;
    float init = base[o] + cb[o];
    float a0 = init, a1 = init, a2 = init, a3 = init;
    for (int e = 0; e < 512; ++e) {
        float w = W2t[e * 1024 + o];
        a0 += xs[0][e] * w; a1 += xs[1][e] * w;
        a2 += xs[2][e] * w; a3 += xs[3][e] * w;
    }
    int b0 = bq * 4;
    y[(size_t)(b0 + 0) * 1024 + o] = a0;
    y[(size_t)(b0 + 1) * 1024 + o] = a1;
    y[(size_t)(b0 + 2) * 1024 + o] = a2;
    y[(size_t)(b0 + 3) * 1024 + o] = a3;
}

// partial scores: grid (8 hc, 128 b), block 256 = 4 waves.
// wave w streams 16 full contiguous rows (nt loads); lane owns s-slots lane*4 + j*256.
__global__ void k_scores2(const float* __restrict__ y, const float* __restrict__ xcol,
                          const float* __restrict__ enc, float* __restrict__ part) {
    int hc = blockIdx.x, b = blockIdx.y, t = threadIdx.x;
    int w = t >> 6, lane = t & 63;
    __shared__ float dl[64];
    __shared__ float red[4 * 2048];
    if (t < 64) {
        int hg = hc * 64 + t;
        float ya = y[b * 1024 + hg];
        float yb_ = y[b * 1024 + 512 + hg];
        float g = ya / (1.0f + expf(-yb_));
        dl[t] = g + xcol[b * 512 + hg];
    }
    __syncthreads();
    v4f a[8];
    #pragma unroll
    for (int j = 0; j < 8; ++j) a[j] = (v4f)(0.f);
    const float* bp = enc + ((size_t)b * 512 + hc * 64 + w * 16) * 2048 + lane * 4;
    for (int r = 0; r < 16; ++r) {
        float dh = dl[w * 16 + r];
        const float* rp = bp + (size_t)r * 2048;
        #pragma unroll
        for (int j = 0; j < 8; ++j) {
            v4f v = ldnt4(rp + j * 256);
            a[j] += dh * v;
        }
    }
    #pragma unroll
    for (int j = 0; j < 8; ++j)
        *(v4f*)&red[w * 2048 + j * 256 + lane * 4] = a[j];
    __syncthreads();
    #pragma unroll
    for (int k = 0; k < 2; ++k) {
        int s = t * 4 + k * 1024;
        v4f s0 = *(const v4f*)&red[0 * 2048 + s];
        v4f s1 = *(const v4f*)&red[1 * 2048 + s];
        v4f s2 = *(const v4f*)&red[2 * 2048 + s];
        v4f s3 = *(const v4f*)&red[3 * 2048 + s];
        *(v4f*)&part[(size_t)hc * 262144 + b * 2048 + s] = (s0 + s1) + (s2 + s3);
    }
}

// sum 8 partials + softmax over S=2048 per batch
__global__ void k_softmax2(const float* __restrict__ part, float* __restrict__ attn) {
    int b = blockIdx.x, t = threadIdx.x;              // block 256
    float v[8];
    float m = -1e30f;
    for (int i = 0; i < 8; ++i) {
        int s = i * 256 + t;
        float acc = 0.f;
        #pragma unroll
        for (int hc = 0; hc < 8; ++hc) acc += part[(size_t)hc * 262144 + b * 2048 + s];
        v[i] = acc; m = fmaxf(m, acc);
    }
    __shared__ float r[256];
    r[t] = m; __syncthreads();
    for (int s = 128; s > 0; s >>= 1) { if (t < s) r[t] = fmaxf(r[t], r[t + s]); __syncthreads(); }
    float M = r[0]; __syncthreads();
    float sum = 0.f;
    for (int i = 0; i < 8; ++i) { v[i] = expf(v[i] - M); sum += v[i]; }
    r[t] = sum; __syncthreads();
    for (int s = 128; s > 0; s >>= 1) { if (t < s) r[t] += r[t + s]; __syncthreads(); }
    float inv = 1.0f / r[0];
    for (int i = 0; i < 8; ++i) attn[b * 2048 + i * 256 + t] = v[i] * inv;
}

// c[b,h] = sum_s attn[b,s]*enc_total[b,h,s];  h_out = glu(y) + c.
// block = 4 waves, one h-row each, same b; attn row staged in LDS; nt enc stream.
__global__ void k_c2(const float* __restrict__ attn, const float* __restrict__ enc,
                     const float* __restrict__ y, float* __restrict__ hbuf) {
    int t = threadIdx.x;                              // block 256, grid 16384
    int b  = blockIdx.x >> 7;
    int h0 = (blockIdx.x & 127) << 2;
    __shared__ float al[2048];
    for (int j = t; j < 2048; j += 256) al[j] = attn[b * 2048 + j];
    __syncthreads();
    int w = t >> 6, lane = t & 63;
    int hh = h0 + w;
    const float* vp = enc + ((size_t)b * 512 + hh) * 2048;
    float acc = 0.f;
    #pragma unroll
    for (int it = 0; it < 8; ++it) {
        int s = it * 256 + lane * 4;
        v4f v = ldnt4(vp + s);
        float4 p = *(const float4*)&al[s];
        acc += p.x * v[0] + p.y * v[1] + p.z * v[2] + p.w * v[3];
    }
    #pragma unroll
    for (int off = 32; off > 0; off >>= 1) acc += __shfl_down(acc, off, 64);
    if (lane == 0) {
        float ya = y[b * 1024 + hh];
        float yb_ = y[b * 1024 + 512 + hh];
        float g = ya / (1.0f + expf(-yb_));
        hbuf[b * 512 + hh] = g + acc;
    }
}

// ---- epilogue (fused logits/log-softmax + softmax over H) ---------------

__global__ void k_epi(const float* __restrict__ h, const float* __restrict__ l2w,
                      const float* __restrict__ l2b, float* __restrict__ out) {
    int b = blockIdx.x, t = threadIdx.x;              // block 256
    __shared__ float hl[512];
    hl[t] = h[b * 512 + t]; hl[t + 256] = h[b * 512 + 256 + t];
    __syncthreads();
    // logits + log_softmax over V=83
    float acc = 0.f;
    if (t < V_) {
        acc = l2b[t];
        for (int e = 0; e < 512; ++e) acc += hl[e] * l2w[t * 512 + e];
    }
    __shared__ float r[256];
    r[t] = (t < V_) ? acc : -1e30f; __syncthreads();
    for (int s = 128; s > 0; s >>= 1) { if (t < s) r[t] = fmaxf(r[t], r[t + s]); __syncthreads(); }
    float M = r[0]; __syncthreads();
    r[t] = (t < V_) ? expf(acc - M) : 0.f; __syncthreads();
    for (int s = 128; s > 0; s >>= 1) { if (t < s) r[t] += r[t + s]; __syncthreads(); }
    float L = M + logf(r[0]);
    if (t < V_) out[65536 + b * V_ + t] = acc - L;
    __syncthreads();
    // softmax over H=512
    float v0 = hl[t], v1 = hl[t + 256];
    r[t] = fmaxf(v0, v1); __syncthreads();
    for (int s = 128; s > 0; s >>= 1) { if (t < s) r[t] = fmaxf(r[t], r[t + s]); __syncthreads(); }
    float M2 = r[0]; __syncthreads();
    float e0 = expf(v0 - M2), e1 = expf(v1 - M2);
    r[t] = e0 + e1; __syncthreads();
    for (int s = 128; s > 0; s >>= 1) { if (t < s) r[t] += r[t + s]; __syncthreads(); }
    float inv = 1.0f / r[0];
    out[b * 512 + t] = e0 * inv;
    out[b * 512 + 256 + t] = e1 * inv;
}

// ---- launch --------------------------------------------------------------

extern "C" void kernel_launch(void* const* d_in, const int* in_sizes, int n_in,
                              void* d_out, int out_size, void* d_ws, size_t ws_size,
                              hipStream_t stream) {
    const float* enc_out = (const float*)d_in[0];   // [B,H,S] f32
    const float* enc_tot = (const float*)d_in[1];   // [B,H,S] f32
    const int*   tok     = (const int*)d_in[2];     // [B] int32
    // d_in[3] = count (==0 path)
    const float* emb     = (const float*)d_in[4];   // [V,E] f32
    const float* conv_w  = (const float*)d_in[5];   // [1024,512,3] f32
    const float* conv_b  = (const float*)d_in[6];   // [1024] f32
    const float* l2w     = (const float*)d_in[7];   // [83,512] f32
    const float* l2b     = (const float*)d_in[8];   // [83] f32
    float* out = (float*)d_out;                     // 65536 + 10624 f32
    float* ws = (float*)d_ws;

    // ws layout (floats)
    float* W2t  = ws;                 // 524288
    float* base = W2t + 524288;       // 1024
    float* pe2  = base + 1024;        // 512
    float* x01i = pe2 + 512;          // 1536
    float* xcol = x01i + 1536;        // 65536
    float* yb   = xcol + 65536;       // 131072
    float* attn = yb + 131072;        // 262144
    float* part = attn + 262144;      // 8*262144 = 2097152
    float* hbuf = part + 2097152;     // 65536
    // total ~12.6 MB

    k_misc<<<1, 512, 0, stream>>>(emb, pe2, x01i);
    k_base3<<<256, 256, 0, stream>>>(conv_w, x01i, base);
    k_prep<<<dim3(16, 4), 256, 0, stream>>>(conv_w, W2t);

    for (int L = 0; L < 3; ++L) {
        k_yx<<<dim3(4, 32), 256, 0, stream>>>(L == 0 ? 1 : 0, tok, emb, hbuf, pe2,
                                              W2t, base, conv_b, xcol, yb);
        k_scores2<<<dim3(8, 128), 256, 0, stream>>>(yb, xcol, enc_out, part);
        k_softmax2<<<128, 256, 0, stream>>>(part, attn);
        k_c2<<<16384, 256, 0, stream>>>(attn, enc_tot, yb, hbuf);
    }

    k_epi<<<128, 256, 0, stream>>>(hbuf, l2w, l2b, out);
}